// Round 5
// baseline (810.075 us; speedup 1.0000x reference)
//
#include <hip/hip_runtime.h>
#include <hip/hip_bf16.h>
#include <math.h>

// Problem constants
#define B_      4
#define T_      4096
#define D_      2048
#define DMEM_   1024
#define H_      16
#define TABLE_  131072
#define NTOK    (B_ * T_)      // 16384 tokens
#define NKV     (2 * D_)       // 4096 packed k|v output columns
#define NT_TILES 16            // K / 64
#define EPS_QK  1.1920928955078125e-07f
#define EPS_CONV 1e-5f
#define INV_D   (1.0f / 2048.0f)
#define INV_SQRT_D 0.02209708691207961f   // 1/sqrt(2048)

typedef __attribute__((ext_vector_type(8))) __bf16 bf16x8;
typedef __attribute__((ext_vector_type(4))) float  f32x4;
typedef __attribute__((ext_vector_type(8))) unsigned short u16x8;

typedef __attribute__((address_space(3))) unsigned int       lds_u32;
typedef const __attribute__((address_space(1))) unsigned int glb_u32;

__device__ __forceinline__ unsigned short f2bf(float f) {
    unsigned u = __float_as_uint(f);
    u += 0x7fff + ((u >> 16) & 1);   // round-to-nearest-even
    return (unsigned short)(u >> 16);
}
__device__ __forceinline__ float bf2f(unsigned short u) {
    return __uint_as_float(((unsigned)u) << 16);
}
__device__ __forceinline__ void gload16(const void* g, void* l) {
    __builtin_amdgcn_global_load_lds((glb_u32*)g, (lds_u32*)l, 16, 0, 0);
}

// 16-lane sum via DPP row_shr (VALU pipe). Sum lands in lane 15 of each group.
#define DSHR(x, n) __int_as_float(__builtin_amdgcn_update_dpp( \
    0, __float_as_int(x), 0x110 + (n), 0xf, 0xf, false))
#define RED16(x) do { x += DSHR(x, 1); x += DSHR(x, 2); \
                      x += DSHR(x, 4); x += DSHR(x, 8); } while (0)

// ---------------------------------------------------------------------------
// 1) prep: gather e (bid < NTOK) OR pack W/bias/qkg + zero stats (bid >= NTOK)
// ---------------------------------------------------------------------------
__global__ __launch_bounds__(256) void prep(
    const int* __restrict__ hash_ids, const float* __restrict__ table,
    const float* __restrict__ kW, const float* __restrict__ vW,
    const float* __restrict__ kb, const float* __restrict__ vb,
    const float* __restrict__ qg, const float* __restrict__ kg,
    unsigned short* __restrict__ e, unsigned short* __restrict__ Wp,
    float* __restrict__ biasP, float* __restrict__ qkg,
    float* __restrict__ gstats /* 4*NTOK floats */)
{
    const int bid = blockIdx.x;
    const int tid = threadIdx.x;
    if (bid < NTOK) {
        const int m = tid * 4;
        const int h = m >> 6;
        const int w = m & 63;
        const long long row = (long long)hash_ids[bid * H_ + h] + (long long)h * TABLE_;
        const float4 v = *(const float4*)(table + (size_t)row * 64 + w);
        ushort4 o;
        o.x = f2bf(v.x); o.y = f2bf(v.y); o.z = f2bf(v.z); o.w = f2bf(v.w);
        *(ushort4*)(e + (size_t)bid * DMEM_ + m) = o;
    } else {
        const int n = bid - NTOK;            // 0..4095
        const int m = tid * 4;
        const float* src = (n < D_) ? (kW + (size_t)n * DMEM_) : (vW + (size_t)(n - D_) * DMEM_);
        const float4 v = *(const float4*)(src + m);
        ushort4 o;
        o.x = f2bf(v.x); o.y = f2bf(v.y); o.z = f2bf(v.z); o.w = f2bf(v.w);
        *(ushort4*)(Wp + (size_t)n * DMEM_ + m) = o;
        if (tid == 0) biasP[n] = (n < D_) ? kb[n] : vb[n - D_];
        if (tid == 1 && n < D_) qkg[n] = qg[n] * kg[n];
        if (tid >= 16 && tid < 32) gstats[n * 16 + (tid - 16)] = 0.0f;
    }
}

// ---------------------------------------------------------------------------
// 2) GEMM: 256x256 tile, BK=64, 8 waves (2Mx4N), 8-phase (T2+T3+T4+T5).
//    Persistent: 256 blocks x 4 tiles (same bm, consecutive bn). Stage-guards
//    wrap (ts&15, next-W panel) so the last 2 K_TILEs of a tile prefetch the
//    next tile's full 7-half prologue; epilogue overlaps the fill and uses
//    the one LDS region the wrap never writes (B dd1 nh0, 16KB @ 98304).
//    bn<8 (k-half): per-row {h2,k2,hk} partials, no store.
//    bn>=8 (v-half): bf16 v store + per-row v2 via direct global atomics.
// ---------------------------------------------------------------------------
#define STAGE_A(dd, mh, ts) do { \
    if ((ts) < NT_TILES || wrapok) { \
        const int tsw_ = (ts) & 15; \
        _Pragma("unroll") \
        for (int c_ = 0; c_ < 2; ++c_) { \
            const int lin_ = c_ * 512 + tid; \
            const int lr_ = lin_ >> 3, c16_ = lin_ & 7; \
            gload16(Ab + (size_t)((lr_ >> 6) * 128 + (mh) * 64 + (lr_ & 63)) * 2048 \
                       + tsw_ * 128 + ((c16_ ^ (lr_ & 7)) << 4), \
                    lds + (dd) * 32768 + (mh) * 16384 + (c_ * 512 + wid * 64) * 16); \
        } \
    } \
} while (0)

#define STAGE_B(dd, nh, ts) do { \
    if ((ts) < NT_TILES || wrapok) { \
        const int tsw_ = (ts) & 15; \
        const char* wp_ = ((ts) < NT_TILES) ? Wb : Wbn; \
        _Pragma("unroll") \
        for (int c_ = 0; c_ < 2; ++c_) { \
            const int lin_ = c_ * 512 + tid; \
            const int lr_ = lin_ >> 3, c16_ = lin_ & 7; \
            gload16(wp_ + (size_t)((lr_ >> 5) * 64 + (nh) * 32 + (lr_ & 31)) * 2048 \
                       + tsw_ * 128 + ((c16_ ^ (lr_ & 7)) << 4), \
                    lds + 65536 + (dd) * 32768 + (nh) * 16384 + (c_ * 512 + wid * 64) * 16); \
        } \
    } \
} while (0)

#define LDA(dd, mh) do { \
    _Pragma("unroll") \
    for (int mi_ = 0; mi_ < 4; ++mi_) { \
        const int l_ = (mh) * 128 + wm * 64 + mi_ * 16 + (lane & 15); \
        _Pragma("unroll") \
        for (int kk_ = 0; kk_ < 2; ++kk_) { \
            const int kb_ = (kk_ * 64 + ((lane >> 4) << 4)) ^ ((lane & 7) << 4); \
            af[mi_][kk_] = *(const bf16x8*)(lds + (dd) * 32768 + l_ * 128 + kb_); \
        } \
    } \
} while (0)

#define LDB(dd, nh) do { \
    _Pragma("unroll") \
    for (int ni_ = 0; ni_ < 2; ++ni_) { \
        const int l_ = (nh) * 128 + wn * 32 + ni_ * 16 + (lane & 15); \
        _Pragma("unroll") \
        for (int kk_ = 0; kk_ < 2; ++kk_) { \
            const int kb_ = (kk_ * 64 + ((lane >> 4) << 4)) ^ ((lane & 7) << 4); \
            bfr[ni_][kk_] = *(const bf16x8*)(lds + 65536 + (dd) * 32768 + l_ * 128 + kb_); \
        } \
    } \
} while (0)

#define MM(mh, nh) do { \
    __builtin_amdgcn_s_setprio(1); \
    _Pragma("unroll") \
    for (int mi_ = 0; mi_ < 4; ++mi_) \
        _Pragma("unroll") \
        for (int ni_ = 0; ni_ < 2; ++ni_) \
            _Pragma("unroll") \
            for (int kk_ = 0; kk_ < 2; ++kk_) \
                acc[(mh) * 4 + mi_][(nh) * 2 + ni_] = \
                    __builtin_amdgcn_mfma_f32_16x16x32_bf16(af[mi_][kk_], bfr[ni_][kk_], \
                        acc[(mh) * 4 + mi_][(nh) * 2 + ni_], 0, 0, 0); \
    __builtin_amdgcn_s_setprio(0); \
} while (0)

#define BAR()  do { __builtin_amdgcn_sched_barrier(0); __builtin_amdgcn_s_barrier(); __builtin_amdgcn_sched_barrier(0); } while (0)
#define BARW() do { __builtin_amdgcn_sched_barrier(0); asm volatile("s_waitcnt lgkmcnt(0)" ::: "memory"); __builtin_amdgcn_s_barrier(); __builtin_amdgcn_sched_barrier(0); } while (0)
#define VMC(n) asm volatile("s_waitcnt vmcnt(" #n ")" ::: "memory")

#define K_TILE(dd, t) do { \
    bf16x8 af[4][2]; bf16x8 bfr[2][2]; \
    LDA(dd, 0); LDB(dd, 0); STAGE_B((dd) ^ 1, 0, (t) + 1); \
    BAR(); MM(0, 0); BAR(); \
    LDB(dd, 1); STAGE_A(dd, 0, (t) + 2); \
    BAR(); MM(0, 1); BAR(); \
    LDA(dd, 1); STAGE_B(dd, 1, (t) + 2); \
    BAR(); MM(1, 1); BAR(); \
    LDB(dd, 0); STAGE_A(dd, 1, (t) + 2); \
    VMC(6); BAR(); MM(1, 0); BAR(); \
} while (0)

__global__ __launch_bounds__(512, 2) void gemm_kv(
    const unsigned short* __restrict__ A,
    const unsigned short* __restrict__ W,
    const float* __restrict__ biasP,
    const float* __restrict__ qkg,
    const float* __restrict__ hid,
    unsigned short* __restrict__ vbuf,
    float* __restrict__ gh2, float* __restrict__ gk2,
    float* __restrict__ ghk, float* __restrict__ gv2)
{
    __shared__ __align__(16) char lds[131072];
    const int tid  = threadIdx.x;
    const int wid  = tid >> 6;
    const int lane = tid & 63;
    const int bid  = blockIdx.x;          // 0..255
    const int j8   = bid >> 3;            // 0..31
    const int bm   = (bid & 7) * 8 + (j8 >> 2);  // same-bm group stays on one XCD
    const int g    = j8 & 3;              // bn-group: 0,1 = k-half; 2,3 = v-half
    const int wm = wid >> 2, wn = wid & 3;
    const int r0 = bm * 256;

    const char* Ab    = (const char*)A + (size_t)r0 * 2048;
    const char* Wbase = (const char*)W;

    for (int cc = 0; cc < 4; ++cc) {
        const int bn = g * 4 + cc;
        const int c0 = bn * 256;
        const char* Wb  = Wbase + (size_t)c0 * 2048;
        const char* Wbn = Wbase + (size_t)(c0 + 256) * 2048;  // used only when wrapok
        const int wrapok = (cc < 3);

        f32x4 acc[8][4] = {};

        if (cc == 0) {
            // First prologue: tile0 fully + tile1 {A0,B1,A1}.
            STAGE_A(0, 0, 0); STAGE_B(0, 0, 0); STAGE_B(0, 1, 0); STAGE_A(0, 1, 0);
            STAGE_A(1, 0, 1); STAGE_B(1, 1, 1); STAGE_A(1, 1, 1);
            VMC(6);
            BAR();
        }

        for (int t = 0; t < NT_TILES; t += 2) {
            K_TILE(0, t);
            K_TILE(1, t + 1);
        }
        // Wrap-staged next-tile prologue (7 halves) is now in flight.
        // Epilogue below uses only lds[98304..114688) — untouched by wrap.

        float breg[4];
#pragma unroll
        for (int ni = 0; ni < 4; ++ni)
            breg[ni] = biasP[c0 + wn * 64 + ni * 16 + (lane & 15)];

        if (g < 2) {
            // ------------- k-half: per-row h2/k2/hk partials, no store ------
            float* sH  = (float*)(lds + 98304);   // [256]
            float* sK  = sH + 256;
            float* sHK = sK + 256;
            for (int i = tid; i < 768; i += 512) sH[i] = 0.0f;
            float qreg[4];
#pragma unroll
            for (int ni = 0; ni < 4; ++ni)
                qreg[ni] = qkg[c0 + wn * 64 + ni * 16 + (lane & 15)];
            BARW();

#pragma unroll
            for (int mi = 0; mi < 8; ++mi) {
                float h2[4] = {}, k2[4] = {}, hk[4] = {};
#pragma unroll
                for (int ni = 0; ni < 4; ++ni) {
#pragma unroll
                    for (int j = 0; j < 4; ++j) {
                        const float kv = acc[mi][ni][j] + breg[ni];
                        const int rl = wm * 128 + mi * 16 + (lane >> 4) * 4 + j;
                        const float hv = hid[(size_t)(r0 + rl) * 2048 + c0
                                             + wn * 64 + ni * 16 + (lane & 15)];
                        h2[j] += hv * hv;
                        k2[j] += kv * kv;
                        hk[j] += hv * qreg[ni] * kv;
                    }
                }
#pragma unroll
                for (int j = 0; j < 4; ++j) {
                    RED16(h2[j]); RED16(k2[j]); RED16(hk[j]);
                }
                if ((lane & 15) == 15) {
#pragma unroll
                    for (int j = 0; j < 4; ++j) {
                        const int rl = wm * 128 + mi * 16 + (lane >> 4) * 4 + j;
                        atomicAdd(&sH[rl], h2[j]);
                        atomicAdd(&sK[rl], k2[j]);
                        atomicAdd(&sHK[rl], hk[j]);
                    }
                }
            }
            BARW();
            if (tid < 256) {
                atomicAdd(&gh2[r0 + tid], sH[tid]);
                atomicAdd(&gk2[r0 + tid], sK[tid]);
                atomicAdd(&ghk[r0 + tid], sHK[tid]);
            }
        } else {
            // ------------- v-half: v2 global atomics + bf16 store ----------
            char* slab = lds + 98304;             // 32 x 512 B
            const int cv0 = (bn - 8) * 256;       // col offset within v

#pragma unroll
            for (int mi = 0; mi < 8; ++mi) {
                float v2[4] = {};
#pragma unroll
                for (int ni = 0; ni < 4; ++ni)
#pragma unroll
                    for (int j = 0; j < 4; ++j) {
                        const float vv = acc[mi][ni][j] + breg[ni];
                        v2[j] += vv * vv;
                    }
#pragma unroll
                for (int j = 0; j < 4; ++j) RED16(v2[j]);
                if ((lane & 15) == 15) {
#pragma unroll
                    for (int j = 0; j < 4; ++j) {
                        const int rl = wm * 128 + mi * 16 + (lane >> 4) * 4 + j;
                        atomicAdd(&gv2[r0 + rl], v2[j]);
                    }
                }
                // slab + coalesced store
#pragma unroll
                for (int ni = 0; ni < 4; ++ni) {
#pragma unroll
                    for (int j = 0; j < 4; ++j) {
                        const int srow = wm * 16 + (lane >> 4) * 4 + j;
                        const int colb = (wn * 64 + ni * 16 + (lane & 15)) * 2;
                        *(unsigned short*)(slab + srow * 512 + (colb ^ (((srow >> 2) & 3) << 5))) =
                            f2bf(acc[mi][ni][j] + breg[ni]);
                    }
                }
                BARW();
#pragma unroll
                for (int c2 = 0; c2 < 4; ++c2) {
                    const int lin = c2 * 512 + tid;
                    const int srow = lin >> 6, cb8 = (lin & 63) * 8;
                    const ushort4 vv = *(const ushort4*)(slab + srow * 512 + (cb8 ^ (((srow >> 2) & 3) << 5)));
                    const int grow = r0 + (srow >> 4) * 128 + mi * 16 + (srow & 15);
                    const int gcol = cv0 + (lin & 63) * 4;
                    *(ushort4*)((char*)vbuf + (size_t)grow * 4096 + gcol * 2) = vv;
                }
                BARW();
            }
        }

        // Drain wrapped prefetch (mostly landed under the epilogue), resync.
        VMC(0);
        BARW();
    }
}

// ---------------------------------------------------------------------------
// 3) convout, row-tiled: 32 out rows x 256 cols per block; 38 v-rows staged
//    in LDS; gate/rinv finalized in-block from the 4 stat arrays.
//    out[t,d] = silu(sum_j w[d,j]*gr[rr]*cg[d]*v[rr,d]) + gate*v[t,d]
// ---------------------------------------------------------------------------
__global__ __launch_bounds__(256) void convout(
    const unsigned short* __restrict__ vbuf,
    const float* __restrict__ gh2, const float* __restrict__ gk2,
    const float* __restrict__ ghk, const float* __restrict__ gv2,
    const float* __restrict__ cg, const float* __restrict__ convw,
    float* __restrict__ out)
{
    __shared__ __align__(16) char vlds[38 * 512];
    __shared__ float sgate[38];
    __shared__ float sgr[38];
    const int bid = blockIdx.x;
    const int by = bid >> 3, bx = bid & 7;
    const int R0 = by * 32, C0 = bx * 256;
    const int tid = threadIdx.x;

    // finalize gate / gate*rinv for rows R0-6 .. R0+31
    if (tid < 38) {
        int r = R0 - 6 + tid; if (r < 0) r = 0;
        const float dot = ghk[r] * rsqrtf(gh2[r] * INV_D + EPS_QK)
                                 * rsqrtf(gk2[r] * INV_D + EPS_QK) * INV_SQRT_D;
        const float sgn = (dot > 0.f) ? 1.f : ((dot < 0.f) ? -1.f : 0.f);
        const float dd = sqrtf(fmaxf(fabsf(dot), 1e-6f)) * sgn;
        const float gg = 1.f / (1.f + expf(-dd));
        sgate[tid] = gg;
        sgr[tid]   = gg * rsqrtf(gg * gg * (gv2[r] * INV_D) + EPS_CONV);
    }

    // stage rows R0-6 .. R0+31, cols C0..C0+255 (bf16), 19456 B
#pragma unroll
    for (int c = 0; c < 5; ++c) {
        const int wbase = c * 4096 + (tid >> 6) * 1024;   // wave-uniform dest
        if (wbase < 19456) {
            const int off = c * 4096 + tid * 16;
            const int i = off >> 9;
            int gsrc = R0 - 6 + i; if (gsrc < 0) gsrc = 0;
            gload16((const char*)vbuf + (size_t)gsrc * 4096 + C0 * 2 + (off & 511),
                    vlds + wbase);
        }
    }
    VMC(0);
    __syncthreads();

    const int cgrp = tid & 31;          // 8-col group
    const int rgrp = tid >> 5;          // 0..7 -> 4 rows each
    const int dcol = C0 + cgrp * 8;
    const int cb = cgrp * 16;           // byte offset in an LDS row

    const float4 ca = *(const float4*)(cg + dcol), cbv = *(const float4*)(cg + dcol + 4);
    const float cgv[8] = {ca.x, ca.y, ca.z, ca.w, cbv.x, cbv.y, cbv.z, cbv.w};
    float w[8][4];
#pragma unroll
    for (int ee = 0; ee < 8; ++ee) {
        const float4 wv = *(const float4*)(convw + (size_t)(dcol + ee) * 4);
        w[ee][0] = wv.x; w[ee][1] = wv.y; w[ee][2] = wv.z; w[ee][3] = wv.w;
    }

#pragma unroll
    for (int rr = 0; rr < 4; ++rr) {
        const int rloc = rgrp * 4 + rr;          // 0..31
        const int row = R0 + rloc;
        const int t = row & (T_ - 1);
        const float g0 = sgate[rloc + 6];

        float acc[8] = {};
#pragma unroll
        for (int j = 0; j < 4; ++j) {
            const int tau = t - 6 + 2 * j;
            if (tau < 0) continue;
            const float s = sgr[rloc + 2 * j];
            const u16x8 vv = *(const u16x8*)(vlds + (rloc + 2 * j) * 512 + cb);
#pragma unroll
            for (int ee = 0; ee < 8; ++ee)
                acc[ee] += w[ee][j] * s * cgv[ee] * bf2f(vv[ee]);
        }

        const u16x8 vown = *(const u16x8*)(vlds + (rloc + 6) * 512 + cb);
        float o[8];
#pragma unroll
        for (int ee = 0; ee < 8; ++ee)
            o[ee] = acc[ee] / (1.f + expf(-acc[ee])) + g0 * bf2f(vown[ee]);

        float* op = out + (size_t)row * D_ + dcol;
        *(float4*)op       = make_float4(o[0], o[1], o[2], o[3]);
        *(float4*)(op + 4) = make_float4(o[4], o[5], o[6], o[7]);
    }
}

// ---------------------------------------------------------------------------
extern "C" void kernel_launch(void* const* d_in, const int* in_sizes, int n_in,
                              void* d_out, int out_size, void* d_ws, size_t ws_size,
                              hipStream_t stream) {
    const float* hid   = (const float*)d_in[0];
    const int*   hash  = (const int*)  d_in[1];
    const float* table = (const float*)d_in[2];
    const float* kW    = (const float*)d_in[3];
    const float* kb    = (const float*)d_in[4];
    const float* vW    = (const float*)d_in[5];
    const float* vb    = (const float*)d_in[6];
    const float* qg    = (const float*)d_in[7];
    const float* kg    = (const float*)d_in[8];
    const float* cg    = (const float*)d_in[9];
    const float* cw    = (const float*)d_in[10];
    float* out = (float*)d_out;

    char* ws = (char*)d_ws;
    unsigned short* e     = (unsigned short*)(ws);                 //  33,554,432 B
    unsigned short* Wp    = (unsigned short*)(ws + 33554432);      //   8,388,608 B
    float*          biasP = (float*)(ws + 41943040);               //      16,384 B
    float*          qkg   = (float*)(ws + 41959424);               //       8,192 B
    unsigned short* vbuf  = (unsigned short*)(ws + 41967616);      //  67,108,864 B
    float*          gh2   = (float*)(ws + 109076480);              //      65,536 B
    float*          gk2   = (float*)(ws + 109142016);              //      65,536 B
    float*          ghk   = (float*)(ws + 109207552);              //      65,536 B
    float*          gv2   = (float*)(ws + 109273088);              //      65,536 B

    prep<<<dim3(NTOK + NKV), dim3(256), 0, stream>>>(hash, table, kW, vW, kb, vb,
                                                     qg, kg, e, Wp, biasP, qkg, gh2);
    gemm_kv<<<dim3(256), dim3(512), 0, stream>>>(e, Wp, biasP, qkg, hid, vbuf,
                                                 gh2, gk2, ghk, gv2);
    convout<<<dim3(4096), dim3(256), 0, stream>>>(vbuf, gh2, gk2, ghk, gv2,
                                                  cg, cw, out);
}

// Round 7
// 230.079 us; speedup vs baseline: 3.5209x; 3.5209x over previous
//
#include <hip/hip_runtime.h>
#include <hip/hip_bf16.h>
#include <math.h>

// Problem constants
#define B_      4
#define T_      4096
#define D_      2048
#define DMEM_   1024
#define H_      16
#define TABLE_  131072
#define NTOK    (B_ * T_)      // 16384 tokens
#define NKV     (2 * D_)       // 4096 packed k|v output columns
#define NT_TILES 16            // K / 64
#define EPS_QK  1.1920928955078125e-07f
#define EPS_CONV 1e-5f
#define INV_D   (1.0f / 2048.0f)
#define INV_SQRT_D 0.02209708691207961f   // 1/sqrt(2048)

typedef __attribute__((ext_vector_type(8))) __bf16 bf16x8;
typedef __attribute__((ext_vector_type(4))) float  f32x4;
typedef __attribute__((ext_vector_type(8))) unsigned short u16x8;

typedef __attribute__((address_space(3))) unsigned int       lds_u32;
typedef const __attribute__((address_space(1))) unsigned int glb_u32;

__device__ __forceinline__ unsigned short f2bf(float f) {
    unsigned u = __float_as_uint(f);
    u += 0x7fff + ((u >> 16) & 1);   // round-to-nearest-even
    return (unsigned short)(u >> 16);
}
__device__ __forceinline__ float bf2f(unsigned short u) {
    return __uint_as_float(((unsigned)u) << 16);
}
__device__ __forceinline__ void gload16(const void* g, void* l) {
    __builtin_amdgcn_global_load_lds((glb_u32*)g, (lds_u32*)l, 16, 0, 0);
}

// 16-lane sum via DPP row_shr (VALU pipe). Sum lands in lane 15 of each group.
#define DSHR(x, n) __int_as_float(__builtin_amdgcn_update_dpp( \
    0, __float_as_int(x), 0x110 + (n), 0xf, 0xf, false))
#define RED16(x) do { x += DSHR(x, 1); x += DSHR(x, 2); \
                      x += DSHR(x, 4); x += DSHR(x, 8); } while (0)

// ---------------------------------------------------------------------------
// 1) prep: gather e (bid < NTOK) OR pack W/bias/qkg + zero stats (bid >= NTOK)
// ---------------------------------------------------------------------------
__global__ __launch_bounds__(256) void prep(
    const int* __restrict__ hash_ids, const float* __restrict__ table,
    const float* __restrict__ kW, const float* __restrict__ vW,
    const float* __restrict__ kb, const float* __restrict__ vb,
    const float* __restrict__ qg, const float* __restrict__ kg,
    unsigned short* __restrict__ e, unsigned short* __restrict__ Wp,
    float* __restrict__ biasP, float* __restrict__ qkg,
    float* __restrict__ gstats /* 4*NTOK floats */)
{
    const int bid = blockIdx.x;
    const int tid = threadIdx.x;
    if (bid < NTOK) {
        const int m = tid * 4;
        const int h = m >> 6;
        const int w = m & 63;
        const long long row = (long long)hash_ids[bid * H_ + h] + (long long)h * TABLE_;
        const float4 v = *(const float4*)(table + (size_t)row * 64 + w);
        ushort4 o;
        o.x = f2bf(v.x); o.y = f2bf(v.y); o.z = f2bf(v.z); o.w = f2bf(v.w);
        *(ushort4*)(e + (size_t)bid * DMEM_ + m) = o;
    } else {
        const int n = bid - NTOK;            // 0..4095
        const int m = tid * 4;
        const float* src = (n < D_) ? (kW + (size_t)n * DMEM_) : (vW + (size_t)(n - D_) * DMEM_);
        const float4 v = *(const float4*)(src + m);
        ushort4 o;
        o.x = f2bf(v.x); o.y = f2bf(v.y); o.z = f2bf(v.z); o.w = f2bf(v.w);
        *(ushort4*)(Wp + (size_t)n * DMEM_ + m) = o;
        if (tid == 0) biasP[n] = (n < D_) ? kb[n] : vb[n - D_];
        if (tid == 1 && n < D_) qkg[n] = qg[n] * kg[n];
        if (tid >= 16 && tid < 32) gstats[n * 16 + (tid - 16)] = 0.0f;
    }
}

// ---------------------------------------------------------------------------
// 2) GEMM: 256x256 tile, BK=64, 8 waves (2Mx4N), 8-phase (T2+T3+T4+T5).
//    Grid 1024. Stage-guards skip phantom tiles >= 16.
//    TAIL-RACE FIX: K_TILE(0,14) issues only 2 real loads, so its VMC(6)
//    does NOT guarantee tile-15's halves landed; a full VMC(0)+BAR is
//    inserted before the final K_TILE(1,15).
//    bn<8  (k-half): reduce tile into per-row {h2,k2,hk} partials, no store.
//    bn>=8 (v-half): store bf16 v to vbuf[16384][2048] + per-row v2 partials.
// ---------------------------------------------------------------------------
#define STAGE_A(dd, mh, ts) do { \
    if ((ts) < NT_TILES) { \
        _Pragma("unroll") \
        for (int c_ = 0; c_ < 2; ++c_) { \
            const int lin_ = c_ * 512 + tid; \
            const int lr_ = lin_ >> 3, c16_ = lin_ & 7; \
            gload16(Ab + (size_t)((lr_ >> 6) * 128 + (mh) * 64 + (lr_ & 63)) * 2048 \
                       + (ts) * 128 + ((c16_ ^ (lr_ & 7)) << 4), \
                    lds + (dd) * 32768 + (mh) * 16384 + (c_ * 512 + wid * 64) * 16); \
        } \
    } \
} while (0)

#define STAGE_B(dd, nh, ts) do { \
    if ((ts) < NT_TILES) { \
        _Pragma("unroll") \
        for (int c_ = 0; c_ < 2; ++c_) { \
            const int lin_ = c_ * 512 + tid; \
            const int lr_ = lin_ >> 3, c16_ = lin_ & 7; \
            gload16(Wb + (size_t)((lr_ >> 5) * 64 + (nh) * 32 + (lr_ & 31)) * 2048 \
                       + (ts) * 128 + ((c16_ ^ (lr_ & 7)) << 4), \
                    lds + 65536 + (dd) * 32768 + (nh) * 16384 + (c_ * 512 + wid * 64) * 16); \
        } \
    } \
} while (0)

#define LDA(dd, mh) do { \
    _Pragma("unroll") \
    for (int mi_ = 0; mi_ < 4; ++mi_) { \
        const int l_ = (mh) * 128 + wm * 64 + mi_ * 16 + (lane & 15); \
        _Pragma("unroll") \
        for (int kk_ = 0; kk_ < 2; ++kk_) { \
            const int kb_ = (kk_ * 64 + ((lane >> 4) << 4)) ^ ((lane & 7) << 4); \
            af[mi_][kk_] = *(const bf16x8*)(lds + (dd) * 32768 + l_ * 128 + kb_); \
        } \
    } \
} while (0)

#define LDB(dd, nh) do { \
    _Pragma("unroll") \
    for (int ni_ = 0; ni_ < 2; ++ni_) { \
        const int l_ = (nh) * 128 + wn * 32 + ni_ * 16 + (lane & 15); \
        _Pragma("unroll") \
        for (int kk_ = 0; kk_ < 2; ++kk_) { \
            const int kb_ = (kk_ * 64 + ((lane >> 4) << 4)) ^ ((lane & 7) << 4); \
            bfr[ni_][kk_] = *(const bf16x8*)(lds + 65536 + (dd) * 32768 + l_ * 128 + kb_); \
        } \
    } \
} while (0)

#define MM(mh, nh) do { \
    __builtin_amdgcn_s_setprio(1); \
    _Pragma("unroll") \
    for (int mi_ = 0; mi_ < 4; ++mi_) \
        _Pragma("unroll") \
        for (int ni_ = 0; ni_ < 2; ++ni_) \
            _Pragma("unroll") \
            for (int kk_ = 0; kk_ < 2; ++kk_) \
                acc[(mh) * 4 + mi_][(nh) * 2 + ni_] = \
                    __builtin_amdgcn_mfma_f32_16x16x32_bf16(af[mi_][kk_], bfr[ni_][kk_], \
                        acc[(mh) * 4 + mi_][(nh) * 2 + ni_], 0, 0, 0); \
    __builtin_amdgcn_s_setprio(0); \
} while (0)

#define BAR()  do { __builtin_amdgcn_sched_barrier(0); __builtin_amdgcn_s_barrier(); __builtin_amdgcn_sched_barrier(0); } while (0)
#define BARW() do { __builtin_amdgcn_sched_barrier(0); asm volatile("s_waitcnt lgkmcnt(0)" ::: "memory"); __builtin_amdgcn_s_barrier(); __builtin_amdgcn_sched_barrier(0); } while (0)
#define VMC(n) asm volatile("s_waitcnt vmcnt(" #n ")" ::: "memory")

#define K_TILE(dd, t) do { \
    bf16x8 af[4][2]; bf16x8 bfr[2][2]; \
    LDA(dd, 0); LDB(dd, 0); STAGE_B((dd) ^ 1, 0, (t) + 1); \
    BAR(); MM(0, 0); BAR(); \
    LDB(dd, 1); STAGE_A(dd, 0, (t) + 2); \
    BAR(); MM(0, 1); BAR(); \
    LDA(dd, 1); STAGE_B(dd, 1, (t) + 2); \
    BAR(); MM(1, 1); BAR(); \
    LDB(dd, 0); STAGE_A(dd, 1, (t) + 2); \
    VMC(6); BAR(); MM(1, 0); BAR(); \
} while (0)

__global__ __launch_bounds__(512, 2) void gemm_kv(
    const unsigned short* __restrict__ A,
    const unsigned short* __restrict__ W,
    const float* __restrict__ biasP,
    const float* __restrict__ qkg,
    const float* __restrict__ hid,
    unsigned short* __restrict__ vbuf,
    float* __restrict__ gh2, float* __restrict__ gk2,
    float* __restrict__ ghk, float* __restrict__ gv2)
{
    __shared__ __align__(16) char lds[131072];
    const int tid  = threadIdx.x;
    const int wid  = tid >> 6;
    const int lane = tid & 63;
    const int bid  = blockIdx.x;
    const int swz  = (bid & 7) * 128 + (bid >> 3);   // XCD swizzle, 1024 % 8 == 0
    const int bm = swz >> 4, bn = swz & 15;          // 64 M-tiles x 16 N-tiles
    const int wm = wid >> 2, wn = wid & 3;           // 2 x 4 waves
    const int r0 = bm * 256, c0 = bn * 256;

    const char* Ab = (const char*)A + (size_t)r0 * 2048;
    const char* Wb = (const char*)W + (size_t)c0 * 2048;

    f32x4 acc[8][4] = {};

    // Prologue: tile0 fully + tile1 {A0,B1,A1}; B0(1) is staged in ph1(0).
    STAGE_A(0, 0, 0); STAGE_B(0, 0, 0); STAGE_B(0, 1, 0); STAGE_A(0, 1, 0);
    STAGE_A(1, 0, 1); STAGE_B(1, 1, 1); STAGE_A(1, 1, 1);
    VMC(6);
    BAR();

    for (int t = 0; t < NT_TILES - 2; t += 2) {
        K_TILE(0, t);
        K_TILE(1, t + 1);
    }
    K_TILE(0, NT_TILES - 2);
    // Tail-race fix: K_TILE(0,14) issued only 2 real loads, so its VMC(6)
    // leaves tile-15's staged halves possibly un-landed. Full drain + barrier
    // before the final tile's ds_reads.
    VMC(0);
    BAR();
    K_TILE(1, NT_TILES - 1);

    VMC(0);   // nothing outstanding, but keep the LDS-reuse ordering explicit
    BARW();

    float breg[4];
#pragma unroll
    for (int ni = 0; ni < 4; ++ni)
        breg[ni] = biasP[c0 + wn * 64 + ni * 16 + (lane & 15)];

    if (bn < 8) {
        // ---------------- k-half: reduce into per-row h2/k2/hk, no store ----
        float* sH  = (float*)lds;          // [256]
        float* sK  = sH + 256;
        float* sHK = sK + 256;
        for (int i = tid; i < 768; i += 512) sH[i] = 0.0f;
        float qreg[4];
#pragma unroll
        for (int ni = 0; ni < 4; ++ni)
            qreg[ni] = qkg[c0 + wn * 64 + ni * 16 + (lane & 15)];
        BARW();

#pragma unroll
        for (int mi = 0; mi < 8; ++mi) {
            float h2[4] = {}, k2[4] = {}, hk[4] = {};
#pragma unroll
            for (int ni = 0; ni < 4; ++ni) {
#pragma unroll
                for (int j = 0; j < 4; ++j) {
                    const float kv = acc[mi][ni][j] + breg[ni];
                    const int rl = wm * 128 + mi * 16 + (lane >> 4) * 4 + j;
                    const float hv = hid[(size_t)(r0 + rl) * 2048 + c0
                                         + wn * 64 + ni * 16 + (lane & 15)];
                    h2[j] += hv * hv;
                    k2[j] += kv * kv;
                    hk[j] += hv * qreg[ni] * kv;
                }
            }
#pragma unroll
            for (int j = 0; j < 4; ++j) {
                RED16(h2[j]); RED16(k2[j]); RED16(hk[j]);
            }
            if ((lane & 15) == 15) {
#pragma unroll
                for (int j = 0; j < 4; ++j) {
                    const int rl = wm * 128 + mi * 16 + (lane >> 4) * 4 + j;
                    atomicAdd(&sH[rl], h2[j]);
                    atomicAdd(&sK[rl], k2[j]);
                    atomicAdd(&sHK[rl], hk[j]);
                }
            }
        }
        BARW();
        if (tid < 256) {
            atomicAdd(&gh2[r0 + tid], sH[tid]);
            atomicAdd(&gk2[r0 + tid], sK[tid]);
            atomicAdd(&ghk[r0 + tid], sHK[tid]);
        }
    } else {
        // ---------------- v-half: v2 partials + bf16 store ------------------
        float* sV = (float*)(lds + 65536);   // [256], B-region free now
        for (int i = tid; i < 256; i += 512) sV[i] = 0.0f;
        BARW();
        const int cv0 = (bn - 8) * 256;      // col offset within v

#pragma unroll
        for (int mi = 0; mi < 8; ++mi) {
            // v^2 partials from f32 acc
            float v2[4] = {};
#pragma unroll
            for (int ni = 0; ni < 4; ++ni)
#pragma unroll
                for (int j = 0; j < 4; ++j) {
                    const float vv = acc[mi][ni][j] + breg[ni];
                    v2[j] += vv * vv;
                }
#pragma unroll
            for (int j = 0; j < 4; ++j) RED16(v2[j]);
            if ((lane & 15) == 15) {
#pragma unroll
                for (int j = 0; j < 4; ++j) {
                    const int rl = wm * 128 + mi * 16 + (lane >> 4) * 4 + j;
                    atomicAdd(&sV[rl], v2[j]);
                }
            }
            // slab + coalesced store
#pragma unroll
            for (int ni = 0; ni < 4; ++ni) {
#pragma unroll
                for (int j = 0; j < 4; ++j) {
                    const int srow = wm * 16 + (lane >> 4) * 4 + j;
                    const int colb = (wn * 64 + ni * 16 + (lane & 15)) * 2;
                    *(unsigned short*)(lds + srow * 512 + (colb ^ (((srow >> 2) & 3) << 5))) =
                        f2bf(acc[mi][ni][j] + breg[ni]);
                }
            }
            BARW();
#pragma unroll
            for (int c2 = 0; c2 < 4; ++c2) {
                const int lin = c2 * 512 + tid;
                const int srow = lin >> 6, cb8 = (lin & 63) * 8;
                const ushort4 vv = *(const ushort4*)(lds + srow * 512 + (cb8 ^ (((srow >> 2) & 3) << 5)));
                const int grow = r0 + (srow >> 4) * 128 + mi * 16 + (srow & 15);
                const int gcol = cv0 + (lin & 63) * 4;
                *(ushort4*)((char*)vbuf + (size_t)grow * 4096 + gcol * 2) = vv;
            }
            BARW();
        }
        if (tid < 256) atomicAdd(&gv2[r0 + tid], sV[tid]);
    }
}

// ---------------------------------------------------------------------------
// 3) convout, row-tiled: 32 out rows x 256 cols per block; 38 v-rows staged
//    in LDS; gate/rinv finalized in-block from the 4 stat arrays.
//    out[t,d] = silu(sum_j w[d,j]*gr[rr]*cg[d]*v[rr,d]) + gate*v[t,d]
// ---------------------------------------------------------------------------
__global__ __launch_bounds__(256) void convout(
    const unsigned short* __restrict__ vbuf,
    const float* __restrict__ gh2, const float* __restrict__ gk2,
    const float* __restrict__ ghk, const float* __restrict__ gv2,
    const float* __restrict__ cg, const float* __restrict__ convw,
    float* __restrict__ out)
{
    __shared__ __align__(16) char vlds[38 * 512];
    __shared__ float sgate[38];
    __shared__ float sgr[38];
    const int bid = blockIdx.x;
    const int by = bid >> 3, bx = bid & 7;
    const int R0 = by * 32, C0 = bx * 256;
    const int tid = threadIdx.x;

    // finalize gate / gate*rinv for rows R0-6 .. R0+31
    if (tid < 38) {
        int r = R0 - 6 + tid; if (r < 0) r = 0;
        const float dot = ghk[r] * rsqrtf(gh2[r] * INV_D + EPS_QK)
                                 * rsqrtf(gk2[r] * INV_D + EPS_QK) * INV_SQRT_D;
        const float sgn = (dot > 0.f) ? 1.f : ((dot < 0.f) ? -1.f : 0.f);
        const float dd = sqrtf(fmaxf(fabsf(dot), 1e-6f)) * sgn;
        const float gg = 1.f / (1.f + expf(-dd));
        sgate[tid] = gg;
        sgr[tid]   = gg * rsqrtf(gg * gg * (gv2[r] * INV_D) + EPS_CONV);
    }

    // stage rows R0-6 .. R0+31, cols C0..C0+255 (bf16), 19456 B
#pragma unroll
    for (int c = 0; c < 5; ++c) {
        const int wbase = c * 4096 + (tid >> 6) * 1024;   // wave-uniform dest
        if (wbase < 19456) {
            const int off = c * 4096 + tid * 16;
            const int i = off >> 9;
            int gsrc = R0 - 6 + i; if (gsrc < 0) gsrc = 0;
            gload16((const char*)vbuf + (size_t)gsrc * 4096 + C0 * 2 + (off & 511),
                    vlds + wbase);
        }
    }
    VMC(0);
    __syncthreads();

    const int cgrp = tid & 31;          // 8-col group
    const int rgrp = tid >> 5;          // 0..7 -> 4 rows each
    const int dcol = C0 + cgrp * 8;
    const int cb = cgrp * 16;           // byte offset in an LDS row

    const float4 ca = *(const float4*)(cg + dcol), cbv = *(const float4*)(cg + dcol + 4);
    const float cgv[8] = {ca.x, ca.y, ca.z, ca.w, cbv.x, cbv.y, cbv.z, cbv.w};
    float w[8][4];
#pragma unroll
    for (int ee = 0; ee < 8; ++ee) {
        const float4 wv = *(const float4*)(convw + (size_t)(dcol + ee) * 4);
        w[ee][0] = wv.x; w[ee][1] = wv.y; w[ee][2] = wv.z; w[ee][3] = wv.w;
    }

#pragma unroll
    for (int rr = 0; rr < 4; ++rr) {
        const int rloc = rgrp * 4 + rr;          // 0..31
        const int row = R0 + rloc;
        const int t = row & (T_ - 1);
        const float g0 = sgate[rloc + 6];

        float acc[8] = {};
#pragma unroll
        for (int j = 0; j < 4; ++j) {
            const int tau = t - 6 + 2 * j;
            if (tau < 0) continue;
            const float s = sgr[rloc + 2 * j];
            const u16x8 vv = *(const u16x8*)(vlds + (rloc + 2 * j) * 512 + cb);
#pragma unroll
            for (int ee = 0; ee < 8; ++ee)
                acc[ee] += w[ee][j] * s * cgv[ee] * bf2f(vv[ee]);
        }

        const u16x8 vown = *(const u16x8*)(vlds + (rloc + 6) * 512 + cb);
        float o[8];
#pragma unroll
        for (int ee = 0; ee < 8; ++ee)
            o[ee] = acc[ee] / (1.f + expf(-acc[ee])) + g0 * bf2f(vown[ee]);

        float* op = out + (size_t)row * D_ + dcol;
        *(float4*)op       = make_float4(o[0], o[1], o[2], o[3]);
        *(float4*)(op + 4) = make_float4(o[4], o[5], o[6], o[7]);
    }
}

// ---------------------------------------------------------------------------
extern "C" void kernel_launch(void* const* d_in, const int* in_sizes, int n_in,
                              void* d_out, int out_size, void* d_ws, size_t ws_size,
                              hipStream_t stream) {
    const float* hid   = (const float*)d_in[0];
    const int*   hash  = (const int*)  d_in[1];
    const float* table = (const float*)d_in[2];
    const float* kW    = (const float*)d_in[3];
    const float* kb    = (const float*)d_in[4];
    const float* vW    = (const float*)d_in[5];
    const float* vb    = (const float*)d_in[6];
    const float* qg    = (const float*)d_in[7];
    const float* kg    = (const float*)d_in[8];
    const float* cg    = (const float*)d_in[9];
    const float* cw    = (const float*)d_in[10];
    float* out = (float*)d_out;

    char* ws = (char*)d_ws;
    unsigned short* e     = (unsigned short*)(ws);                 //  33,554,432 B
    unsigned short* Wp    = (unsigned short*)(ws + 33554432);      //   8,388,608 B
    float*          biasP = (float*)(ws + 41943040);               //      16,384 B
    float*          qkg   = (float*)(ws + 41959424);               //       8,192 B
    unsigned short* vbuf  = (unsigned short*)(ws + 41967616);      //  67,108,864 B
    float*          gh2   = (float*)(ws + 109076480);              //      65,536 B
    float*          gk2   = (float*)(ws + 109142016);              //      65,536 B
    float*          ghk   = (float*)(ws + 109207552);              //      65,536 B
    float*          gv2   = (float*)(ws + 109273088);              //      65,536 B

    prep<<<dim3(NTOK + NKV), dim3(256), 0, stream>>>(hash, table, kW, vW, kb, vb,
                                                     qg, kg, e, Wp, biasP, qkg, gh2);
    gemm_kv<<<dim3(1024), dim3(512), 0, stream>>>(e, Wp, biasP, qkg, hid, vbuf,
                                                  gh2, gk2, ghk, gv2);
    convout<<<dim3(4096), dim3(256), 0, stream>>>(vbuf, gh2, gk2, ghk, gv2,
                                                  cg, cw, out);
}